// Round 20
// baseline (428.223 us; speedup 1.0000x reference)
//
#include <hip/hip_runtime.h>
#include <hip/hip_bf16.h>

typedef float f32x4 __attribute__((ext_vector_type(4)));
typedef short bf16x8 __attribute__((ext_vector_type(8)));
typedef unsigned short u16;

#define NHEADS 6
#define CIN 192
#define HD 32
#define IMG 256
#define YS_ST 200   // bf16 elems; 400B row stride
#define QK_ST 40    // 80B rows (16B-aligned)
#define VT_ST 72    // 144B rows
#define P_ST  72
#define NWIN 4096
#define HS_BYTES 2080   // per-wave halo scratch: float[4][10][13]

// RNE float->bf16 (compiler sequence). HW v_cvt_pk_bf16_f32 truncates and
// FAILED accuracy (R10: absmax 6.7e-2) -- do not substitute.
__device__ __forceinline__ u16 f2bf(float f) {
    __hip_bfloat16 t = __float2bfloat16(f);
    return *reinterpret_cast<u16*>(&t);
}

// Depthwise 3x3 via LDS halo staging (R12 structure -- the proven 301us form).
// Software-pipelining this loop REGRESSED twice (R13 +54, R19 +44): dw load
// latency is already TLP-hidden; keep it simple.
template<bool CHK>
__device__ __forceinline__ void dwphase(const float* __restrict__ x,
                                        const float* __restrict__ dww,
                                        const float* __restrict__ dwb,
                                        u16 (*ys)[YS_ST],
                                        float (*hs)[10][13],
                                        int b, int r0, int c0, int lane, int wave) {
    const int pi = lane >> 3, pj = lane & 7;
    const int lr = lane / 10;          // 0..6
    const int lc = lane - lr * 10;     // 0..9
    const bool ldact = lane < 50;
#pragma unroll 1
    for (int cb = wave * 4; cb < CIN; cb += 16) {
        float hv[4][2];
#pragma unroll
        for (int u = 0; u < 4; ++u) {
            const float* xp = x + (((size_t)(b * CIN + cb + u)) << 16);
#pragma unroll
            for (int s = 0; s < 2; ++s) {
                const int rr = s * 5 + lr;
                const int gy = r0 - 1 + rr;
                const int gx = c0 - 1 + lc;
                float v = 0.f;
                if (ldact && (!CHK || ((unsigned)gy < (unsigned)IMG &&
                                       (unsigned)gx < (unsigned)IMG)))
                    v = xp[gy * IMG + gx];
                hv[u][s] = v;
            }
        }
#pragma unroll
        for (int u = 0; u < 4; ++u)
#pragma unroll
            for (int s = 0; s < 2; ++s)
                if (ldact) hs[u][s * 5 + lr][lc] = hv[u][s];
        float acc[4];
#pragma unroll
        for (int u = 0; u < 4; ++u) acc[u] = dwb[cb + u];
#pragma unroll
        for (int di = 0; di < 3; ++di)
#pragma unroll
            for (int dj = 0; dj < 3; ++dj)
#pragma unroll
                for (int u = 0; u < 4; ++u)
                    acc[u] += hs[u][pi + di][pj + dj] * dww[(cb + u) * 9 + di * 3 + dj];
        const unsigned lo = ((unsigned)f2bf(acc[1]) << 16) | f2bf(acc[0]);
        const unsigned hi = ((unsigned)f2bf(acc[3]) << 16) | f2bf(acc[2]);
        uint2 pk; pk.x = lo; pk.y = hi;
        *(uint2*)&ys[lane][cb] = pk;
    }
}

// One block per 8x8 window; 256 threads = 4 waves. (256,4): proven no-spill point
// (R16: hint 5 -> cap 48 -> spill, FETCH 3x, dur +58%).
// R20 delta vs R14: BOTH q/k col-tiles' weight frags loaded in ONE batch of 12
// independent 16B loads before any MFMA (was 2 batches of 6 with an exposed
// ~250cy L2 wait between) -> one latency exposure per head instead of two.
__global__ __launch_bounds__(256, 4)
void fused_winattn_mfma(const float* __restrict__ x,
                        const float* __restrict__ dww,
                        const float* __restrict__ dwb,
                        const float* __restrict__ pww,
                        const float* __restrict__ pwb,
                        const u16* __restrict__ wbf,
                        float* __restrict__ out) {
    __shared__ __align__(16) unsigned char smem[25600 + 4 * HS_BYTES];   // 33920
    u16 (*ys)[YS_ST] = (u16 (*)[YS_ST])smem;            // dead after afr load
    u16 (*qs)[QK_ST] = (u16 (*)[QK_ST])smem;            // [0, 5120)
    u16 (*ks)[QK_ST] = (u16 (*)[QK_ST])(smem + 5120);   // [5120, 10240)
    u16 (*vt)[VT_ST] = (u16 (*)[VT_ST])(smem + 10240);  // [10240, 14848)
    u16 (*ps)[P_ST]  = (u16 (*)[P_ST]) (smem + 14848);  // [14848, 24064)

    // XCD-aware swizzle (4096 blocks, 8 XCDs -> 512 consecutive windows per XCD)
    const int bid = blockIdx.x;
    const int wb  = (bid & 7) * 512 + (bid >> 3);
    const int b   = wb >> 10;
    const int wy  = (wb >> 5) & 31;
    const int wx  = wb & 31;
    const int r0 = wy << 3, c0 = wx << 3;
    const int tid  = threadIdx.x;
    const int lane = tid & 63;
    const int wave = __builtin_amdgcn_readfirstlane(tid >> 6);
    const int l15 = lane & 15;
    const int l4  = lane >> 4;

    float (*hs)[10][13] = (float (*)[10][13])(smem + 25600 + wave * HS_BYTES);

    // ---------- depthwise 3x3 + bias -> ys bf16 ----------
    if ((unsigned)(wy - 1) < 30u && (unsigned)(wx - 1) < 30u)
        dwphase<false>(x, dww, dwb, ys, hs, b, r0, c0, lane, wave);
    else
        dwphase<true>(x, dww, dwb, ys, hs, b, r0, c0, lane, wave);
    __syncthreads();

    // ---------- A-fragments (persist across all heads) ----------
    const int wr = wave >> 1, wc = wave & 1;
    bf16x8 afr[2][6];
#pragma unroll
    for (int rt = 0; rt < 2; ++rt) {
        const u16* ab = &ys[wr * 32 + rt * 16 + l15][l4 * 8];
#pragma unroll
        for (int kt = 0; kt < 6; ++kt)
            afr[rt][kt] = *(const bf16x8*)(ab + kt * 32);
    }
    __syncthreads();   // ys dead; overlay live from here

    const int m0 = wave * 16;

#pragma unroll 1
    for (int h = 0; h < NHEADS; ++h) {
        // ---- pointwise q-or-k: BOTH col tiles' frags loaded in one batch ----
        const int qkbase = (wc ? CIN : 0) + h * HD;
        f32x4 acc[2][2];   // [ct][rt]
        bf16x8 bfrq[2][6];
#pragma unroll
        for (int ct = 0; ct < 2; ++ct) {
            const int ocrow = qkbase + ct * 16 + l15;
            if (wbf) {
                const u16* wp = wbf + (size_t)ocrow * CIN + l4 * 8;
#pragma unroll
                for (int kt = 0; kt < 6; ++kt) bfrq[ct][kt] = *(const bf16x8*)(wp + kt * 32);
            } else {
                const float* wp = pww + (size_t)ocrow * CIN + l4 * 8;
#pragma unroll
                for (int kt = 0; kt < 6; ++kt) {
                    union { u16 u[8]; bf16x8 v; } cv;
#pragma unroll
                    for (int i = 0; i < 8; ++i) cv.u[i] = f2bf(wp[kt * 32 + i]);
                    bfrq[ct][kt] = cv.v;
                }
            }
            const float bias = pwb[ocrow];
            acc[ct][0] = (f32x4){bias, bias, bias, bias};
            acc[ct][1] = acc[ct][0];
        }
        __builtin_amdgcn_s_setprio(1);
#pragma unroll
        for (int ct = 0; ct < 2; ++ct)
#pragma unroll
            for (int kt = 0; kt < 6; ++kt) {
                acc[ct][0] = __builtin_amdgcn_mfma_f32_16x16x32_bf16(afr[0][kt], bfrq[ct][kt], acc[ct][0], 0, 0, 0);
                acc[ct][1] = __builtin_amdgcn_mfma_f32_16x16x32_bf16(afr[1][kt], bfrq[ct][kt], acc[ct][1], 0, 0, 0);
            }
        __builtin_amdgcn_s_setprio(0);
#pragma unroll
        for (int rt = 0; rt < 2; ++rt) {
            f32x4 s;
#pragma unroll
            for (int i = 0; i < 4; ++i)
                s[i] = acc[0][rt][i] * acc[0][rt][i] + acc[1][rt][i] * acc[1][rt][i];
#pragma unroll
            for (int off = 1; off < 16; off <<= 1) {
#pragma unroll
                for (int i = 0; i < 4; ++i) s[i] += __shfl_xor(s[i], off);
            }
#pragma unroll
            for (int i = 0; i < 4; ++i) {
                const float inv = __builtin_amdgcn_rsqf(fmaxf(s[i], 1e-24f));
                acc[0][rt][i] *= inv;
                acc[1][rt][i] *= inv;
            }
            const int pxr = wr * 32 + rt * 16 + l4 * 4;
            u16 (*dst)[QK_ST] = wc ? ks : qs;
#pragma unroll
            for (int ct = 0; ct < 2; ++ct)
#pragma unroll
                for (int i = 0; i < 4; ++i)
                    dst[pxr + i][ct * 16 + l15] = f2bf(acc[ct][rt][i]);
        }
        // ---- v tile (16 dims per wave-colgroup), packed b64 transposed writes ----
        {
            const int ocrow = 2 * CIN + h * HD + wc * 16 + l15;
            const float bias = pwb[ocrow];
            f32x4 av0 = (f32x4){bias, bias, bias, bias};
            f32x4 av1 = av0;
            bf16x8 bfr[6];
            if (wbf) {
                const u16* wp = wbf + (size_t)ocrow * CIN + l4 * 8;
#pragma unroll
                for (int kt = 0; kt < 6; ++kt) bfr[kt] = *(const bf16x8*)(wp + kt * 32);
            } else {
                const float* wp = pww + (size_t)ocrow * CIN + l4 * 8;
#pragma unroll
                for (int kt = 0; kt < 6; ++kt) {
                    union { u16 u[8]; bf16x8 v; } cv;
#pragma unroll
                    for (int i = 0; i < 8; ++i) cv.u[i] = f2bf(wp[kt * 32 + i]);
                    bfr[kt] = cv.v;
                }
            }
            __builtin_amdgcn_s_setprio(1);
#pragma unroll
            for (int kt = 0; kt < 6; ++kt) {
                av0 = __builtin_amdgcn_mfma_f32_16x16x32_bf16(afr[0][kt], bfr[kt], av0, 0, 0, 0);
                av1 = __builtin_amdgcn_mfma_f32_16x16x32_bf16(afr[1][kt], bfr[kt], av1, 0, 0, 0);
            }
            __builtin_amdgcn_s_setprio(0);
#pragma unroll
            for (int rt = 0; rt < 2; ++rt) {
                const f32x4 a = rt ? av1 : av0;
                const int pxr = wr * 32 + rt * 16 + l4 * 4;
                const unsigned lo = ((unsigned)f2bf(a[1]) << 16) | f2bf(a[0]);
                const unsigned hi = ((unsigned)f2bf(a[3]) << 16) | f2bf(a[2]);
                uint2 pk; pk.x = lo; pk.y = hi;
                *(uint2*)&vt[wc * 16 + l15][pxr] = pk;
            }
        }
        __syncthreads();

        // ---- swapped QK^T: S^T = mfma(K, Q) -> lane-local softmax ----
        const bf16x8 aq = *(const bf16x8*)&qs[m0 + l15][l4 * 8];
        f32x4 st[4];
        __builtin_amdgcn_s_setprio(1);
#pragma unroll
        for (int ct = 0; ct < 4; ++ct) {
            f32x4 z = {0.f, 0.f, 0.f, 0.f};
            const bf16x8 ak = *(const bf16x8*)&ks[ct * 16 + l15][l4 * 8];
            st[ct] = __builtin_amdgcn_mfma_f32_16x16x32_bf16(ak, aq, z, 0, 0, 0);
        }
        __builtin_amdgcn_s_setprio(0);
        // cosine logits bounded in [-1,1] -> no max-subtraction needed
        float sum = 0.f;
#pragma unroll
        for (int ct = 0; ct < 4; ++ct)
#pragma unroll
            for (int i = 0; i < 4; ++i) {
                st[ct][i] = __expf(st[ct][i]);
                sum += st[ct][i];
            }
        sum += __shfl_xor(sum, 16);
        sum += __shfl_xor(sum, 32);
        const float rs = __builtin_amdgcn_rcpf(sum);
#pragma unroll
        for (int ct = 0; ct < 4; ++ct) {
            const unsigned lo = ((unsigned)f2bf(st[ct][1] * rs) << 16) | f2bf(st[ct][0] * rs);
            const unsigned hi = ((unsigned)f2bf(st[ct][3] * rs) << 16) | f2bf(st[ct][2] * rs);
            uint2 pk; pk.x = lo; pk.y = hi;
            *(uint2*)&ps[m0 + l15][ct * 16 + l4 * 4] = pk;
        }
        // ps rows [m0, m0+16) wave-local -> no barrier

        // ---- PV (64x32, K=64) + coalesced store ----
        const bf16x8 ap0 = *(const bf16x8*)&ps[m0 + l15][l4 * 8];
        const bf16x8 ap1 = *(const bf16x8*)&ps[m0 + l15][32 + l4 * 8];
#pragma unroll
        for (int nt = 0; nt < 2; ++nt) {
            f32x4 oa = {0.f, 0.f, 0.f, 0.f};
            const bf16x8 bv0 = *(const bf16x8*)&vt[nt * 16 + l15][l4 * 8];
            const bf16x8 bv1 = *(const bf16x8*)&vt[nt * 16 + l15][32 + l4 * 8];
            __builtin_amdgcn_s_setprio(1);
            oa = __builtin_amdgcn_mfma_f32_16x16x32_bf16(ap0, bv0, oa, 0, 0, 0);
            oa = __builtin_amdgcn_mfma_f32_16x16x32_bf16(ap1, bv1, oa, 0, 0, 0);
            __builtin_amdgcn_s_setprio(0);
            const int dim = h * HD + nt * 16 + l15;
            const int pxr = m0 + l4 * 4;
            const int py = r0 + (pxr >> 3), pxc = c0 + (pxr & 7);
            float* op = out + (((size_t)(b * CIN + dim)) << 16) + py * IMG + pxc;
            *(f32x4*)op = oa;
        }
        __syncthreads();   // buffers reusable next head
    }
}

__global__ void cvt_w(const float* __restrict__ w, u16* __restrict__ o, int n) {
    const int i = blockIdx.x * 256 + threadIdx.x;
    if (i < n) o[i] = f2bf(w[i]);
}

extern "C" void kernel_launch(void* const* d_in, const int* in_sizes, int n_in,
                              void* d_out, int out_size, void* d_ws, size_t ws_size,
                              hipStream_t stream) {
    const float* x   = (const float*)d_in[0];
    const float* dww = (const float*)d_in[1];
    const float* dwb = (const float*)d_in[2];
    const float* pww = (const float*)d_in[3];
    const float* pwb = (const float*)d_in[4];
    float* out = (float*)d_out;

    const int nw = 3 * CIN * CIN;
    u16* wbf = nullptr;
    if (ws_size >= (size_t)nw * sizeof(u16)) {
        wbf = (u16*)d_ws;
        hipLaunchKernelGGL(cvt_w, dim3(nw / 256), dim3(256), 0, stream, pww, wbf, nw);
    }
    hipLaunchKernelGGL(fused_winattn_mfma, dim3(NWIN), dim3(256), 0, stream,
                       x, dww, dwb, pww, pwb, wbf, out);
}

// Round 21
// 300.645 us; speedup vs baseline: 1.4243x; 1.4243x over previous
//
#include <hip/hip_runtime.h>
#include <hip/hip_bf16.h>

typedef float f32x4 __attribute__((ext_vector_type(4)));
typedef short bf16x8 __attribute__((ext_vector_type(8)));
typedef unsigned short u16;

#define NHEADS 6
#define CIN 192
#define HD 32
#define IMG 256
#define YS_ST 200   // bf16 elems; 400B row stride
#define QK_ST 40    // 80B rows (16B-aligned)
#define VT_ST 72    // 144B rows
#define P_ST  72
#define NWIN 4096
#define HS_BYTES 2080   // per-wave halo scratch: float[4][10][13]

// RNE float->bf16 (compiler sequence). HW v_cvt_pk_bf16_f32 truncates and
// FAILED accuracy (R10: absmax 6.7e-2) -- do not substitute.
__device__ __forceinline__ u16 f2bf(float f) {
    __hip_bfloat16 t = __float2bfloat16(f);
    return *reinterpret_cast<u16*>(&t);
}

// Depthwise 3x3 via LDS halo staging: per 4-channel iter, 50 lanes load the
// 10x10 halo (row-batched loads, ~10 segs vs 72 naive -> 3.6x fewer VMEM
// transactions; R12's -64us win). Wave-private hs -> no barrier.
// DO NOT software-pipeline this loop (R13 +54us, R19 +44us: extra live state
// and instructions cost more than the TLP-hidden latency saves).
template<bool CHK>
__device__ __forceinline__ void dwphase(const float* __restrict__ x,
                                        const float* __restrict__ dww,
                                        const float* __restrict__ dwb,
                                        u16 (*ys)[YS_ST],
                                        float (*hs)[10][13],
                                        int b, int r0, int c0, int lane, int wave) {
    const int pi = lane >> 3, pj = lane & 7;
    const int lr = lane / 10;          // 0..6
    const int lc = lane - lr * 10;     // 0..9
    const bool ldact = lane < 50;
#pragma unroll 1
    for (int cb = wave * 4; cb < CIN; cb += 16) {
        float hv[4][2];
#pragma unroll
        for (int u = 0; u < 4; ++u) {
            const float* xp = x + (((size_t)(b * CIN + cb + u)) << 16);
#pragma unroll
            for (int s = 0; s < 2; ++s) {
                const int rr = s * 5 + lr;
                const int gy = r0 - 1 + rr;
                const int gx = c0 - 1 + lc;
                float v = 0.f;
                if (ldact && (!CHK || ((unsigned)gy < (unsigned)IMG &&
                                       (unsigned)gx < (unsigned)IMG)))
                    v = xp[gy * IMG + gx];
                hv[u][s] = v;
            }
        }
#pragma unroll
        for (int u = 0; u < 4; ++u)
#pragma unroll
            for (int s = 0; s < 2; ++s)
                if (ldact) hs[u][s * 5 + lr][lc] = hv[u][s];
        float acc[4];
#pragma unroll
        for (int u = 0; u < 4; ++u) acc[u] = dwb[cb + u];
#pragma unroll
        for (int di = 0; di < 3; ++di)
#pragma unroll
            for (int dj = 0; dj < 3; ++dj)
#pragma unroll
                for (int u = 0; u < 4; ++u)
                    acc[u] += hs[u][pi + di][pj + dj] * dww[(cb + u) * 9 + di * 3 + dj];
        const unsigned lo = ((unsigned)f2bf(acc[1]) << 16) | f2bf(acc[0]);
        const unsigned hi = ((unsigned)f2bf(acc[3]) << 16) | f2bf(acc[2]);
        uint2 pk; pk.x = lo; pk.y = hi;
        *(uint2*)&ys[lane][cb] = pk;
    }
}

// One block per 8x8 window; 256 threads = 4 waves.
// (256,4) is the proven operating point: hint 5/6 -> VGPR cap 48/40 -> scratch
// spill (R16: FETCH 3x, +58%; R7/R9 same). Batching more weight frags in
// registers also spills (R20: FETCH 2.4x, +42%). The head-loop phases must
// stay sequential with the minimal live set.
__global__ __launch_bounds__(256, 4)
void fused_winattn_mfma(const float* __restrict__ x,
                        const float* __restrict__ dww,
                        const float* __restrict__ dwb,
                        const float* __restrict__ pww,
                        const float* __restrict__ pwb,
                        const u16* __restrict__ wbf,
                        float* __restrict__ out) {
    __shared__ __align__(16) unsigned char smem[25600 + 4 * HS_BYTES];   // 33920
    u16 (*ys)[YS_ST] = (u16 (*)[YS_ST])smem;            // dead after afr load
    u16 (*qs)[QK_ST] = (u16 (*)[QK_ST])smem;            // [0, 5120)
    u16 (*ks)[QK_ST] = (u16 (*)[QK_ST])(smem + 5120);   // [5120, 10240)
    u16 (*vt)[VT_ST] = (u16 (*)[VT_ST])(smem + 10240);  // [10240, 14848)
    u16 (*ps)[P_ST]  = (u16 (*)[P_ST]) (smem + 14848);  // [14848, 24064)

    // XCD-aware swizzle (4096 blocks, 8 XCDs -> 512 consecutive windows per XCD;
    // R5: FETCH 605->116MB via halo L2 reuse)
    const int bid = blockIdx.x;
    const int wb  = (bid & 7) * 512 + (bid >> 3);
    const int b   = wb >> 10;
    const int wy  = (wb >> 5) & 31;
    const int wx  = wb & 31;
    const int r0 = wy << 3, c0 = wx << 3;
    const int tid  = threadIdx.x;
    const int lane = tid & 63;
    const int wave = __builtin_amdgcn_readfirstlane(tid >> 6);
    const int l15 = lane & 15;
    const int l4  = lane >> 4;

    float (*hs)[10][13] = (float (*)[10][13])(smem + 25600 + wave * HS_BYTES);

    // ---------- depthwise 3x3 + bias -> ys bf16 ----------
    if ((unsigned)(wy - 1) < 30u && (unsigned)(wx - 1) < 30u)
        dwphase<false>(x, dww, dwb, ys, hs, b, r0, c0, lane, wave);
    else
        dwphase<true>(x, dww, dwb, ys, hs, b, r0, c0, lane, wave);
    __syncthreads();

    // ---------- A-fragments (persist across all heads; 48 VGPR) ----------
    const int wr = wave >> 1, wc = wave & 1;
    bf16x8 afr[2][6];
#pragma unroll
    for (int rt = 0; rt < 2; ++rt) {
        const u16* ab = &ys[wr * 32 + rt * 16 + l15][l4 * 8];
#pragma unroll
        for (int kt = 0; kt < 6; ++kt)
            afr[rt][kt] = *(const bf16x8*)(ab + kt * 32);
    }
    __syncthreads();   // ys dead; overlay live from here

    const int m0 = wave * 16;

    // rolled head loop (R17: code-size null but no cost; keeps L1I cold-miss low)
#pragma unroll 1
    for (int h = 0; h < NHEADS; ++h) {
        // ---- pointwise q-or-k (2 col tiles, loads interleaved per-tile), norms in-register ----
        const int qkbase = (wc ? CIN : 0) + h * HD;
        f32x4 acc[2][2];   // [ct][rt]
#pragma unroll
        for (int ct = 0; ct < 2; ++ct) {
            const int ocrow = qkbase + ct * 16 + l15;
            const float bias = pwb[ocrow];
            acc[ct][0] = (f32x4){bias, bias, bias, bias};
            acc[ct][1] = acc[ct][0];
            bf16x8 bfr[6];
            if (wbf) {
                const u16* wp = wbf + (size_t)ocrow * CIN + l4 * 8;
#pragma unroll
                for (int kt = 0; kt < 6; ++kt) bfr[kt] = *(const bf16x8*)(wp + kt * 32);
            } else {
                const float* wp = pww + (size_t)ocrow * CIN + l4 * 8;
#pragma unroll
                for (int kt = 0; kt < 6; ++kt) {
                    union { u16 u[8]; bf16x8 v; } cv;
#pragma unroll
                    for (int i = 0; i < 8; ++i) cv.u[i] = f2bf(wp[kt * 32 + i]);
                    bfr[kt] = cv.v;
                }
            }
            __builtin_amdgcn_s_setprio(1);
#pragma unroll
            for (int kt = 0; kt < 6; ++kt) {
                acc[ct][0] = __builtin_amdgcn_mfma_f32_16x16x32_bf16(afr[0][kt], bfr[kt], acc[ct][0], 0, 0, 0);
                acc[ct][1] = __builtin_amdgcn_mfma_f32_16x16x32_bf16(afr[1][kt], bfr[kt], acc[ct][1], 0, 0, 0);
            }
            __builtin_amdgcn_s_setprio(0);
        }
#pragma unroll
        for (int rt = 0; rt < 2; ++rt) {
            f32x4 s;
#pragma unroll
            for (int i = 0; i < 4; ++i)
                s[i] = acc[0][rt][i] * acc[0][rt][i] + acc[1][rt][i] * acc[1][rt][i];
#pragma unroll
            for (int off = 1; off < 16; off <<= 1) {
#pragma unroll
                for (int i = 0; i < 4; ++i) s[i] += __shfl_xor(s[i], off);
            }
#pragma unroll
            for (int i = 0; i < 4; ++i) {
                const float inv = __builtin_amdgcn_rsqf(fmaxf(s[i], 1e-24f));
                acc[0][rt][i] *= inv;
                acc[1][rt][i] *= inv;
            }
            const int pxr = wr * 32 + rt * 16 + l4 * 4;
            u16 (*dst)[QK_ST] = wc ? ks : qs;
#pragma unroll
            for (int ct = 0; ct < 2; ++ct)
#pragma unroll
                for (int i = 0; i < 4; ++i)
                    dst[pxr + i][ct * 16 + l15] = f2bf(acc[ct][rt][i]);
        }
        // ---- v tile (16 dims per wave-colgroup), packed b64 transposed writes ----
        {
            const int ocrow = 2 * CIN + h * HD + wc * 16 + l15;
            const float bias = pwb[ocrow];
            f32x4 av0 = (f32x4){bias, bias, bias, bias};
            f32x4 av1 = av0;
            bf16x8 bfr[6];
            if (wbf) {
                const u16* wp = wbf + (size_t)ocrow * CIN + l4 * 8;
#pragma unroll
                for (int kt = 0; kt < 6; ++kt) bfr[kt] = *(const bf16x8*)(wp + kt * 32);
            } else {
                const float* wp = pww + (size_t)ocrow * CIN + l4 * 8;
#pragma unroll
                for (int kt = 0; kt < 6; ++kt) {
                    union { u16 u[8]; bf16x8 v; } cv;
#pragma unroll
                    for (int i = 0; i < 8; ++i) cv.u[i] = f2bf(wp[kt * 32 + i]);
                    bfr[kt] = cv.v;
                }
            }
            __builtin_amdgcn_s_setprio(1);
#pragma unroll
            for (int kt = 0; kt < 6; ++kt) {
                av0 = __builtin_amdgcn_mfma_f32_16x16x32_bf16(afr[0][kt], bfr[kt], av0, 0, 0, 0);
                av1 = __builtin_amdgcn_mfma_f32_16x16x32_bf16(afr[1][kt], bfr[kt], av1, 0, 0, 0);
            }
            __builtin_amdgcn_s_setprio(0);
#pragma unroll
            for (int rt = 0; rt < 2; ++rt) {
                const f32x4 a = rt ? av1 : av0;
                const int pxr = wr * 32 + rt * 16 + l4 * 4;
                const unsigned lo = ((unsigned)f2bf(a[1]) << 16) | f2bf(a[0]);
                const unsigned hi = ((unsigned)f2bf(a[3]) << 16) | f2bf(a[2]);
                uint2 pk; pk.x = lo; pk.y = hi;
                *(uint2*)&vt[wc * 16 + l15][pxr] = pk;
            }
        }
        __syncthreads();

        // ---- swapped QK^T: S^T = mfma(K, Q) -> lane-local softmax ----
        const bf16x8 aq = *(const bf16x8*)&qs[m0 + l15][l4 * 8];
        f32x4 st[4];
        __builtin_amdgcn_s_setprio(1);
#pragma unroll
        for (int ct = 0; ct < 4; ++ct) {
            f32x4 z = {0.f, 0.f, 0.f, 0.f};
            const bf16x8 ak = *(const bf16x8*)&ks[ct * 16 + l15][l4 * 8];
            st[ct] = __builtin_amdgcn_mfma_f32_16x16x32_bf16(ak, aq, z, 0, 0, 0);
        }
        __builtin_amdgcn_s_setprio(0);
        // cosine logits bounded in [-1,1] -> no max-subtraction needed
        float sum = 0.f;
#pragma unroll
        for (int ct = 0; ct < 4; ++ct)
#pragma unroll
            for (int i = 0; i < 4; ++i) {
                st[ct][i] = __expf(st[ct][i]);
                sum += st[ct][i];
            }
        sum += __shfl_xor(sum, 16);
        sum += __shfl_xor(sum, 32);
        const float rs = __builtin_amdgcn_rcpf(sum);
#pragma unroll
        for (int ct = 0; ct < 4; ++ct) {
            const unsigned lo = ((unsigned)f2bf(st[ct][1] * rs) << 16) | f2bf(st[ct][0] * rs);
            const unsigned hi = ((unsigned)f2bf(st[ct][3] * rs) << 16) | f2bf(st[ct][2] * rs);
            uint2 pk; pk.x = lo; pk.y = hi;
            *(uint2*)&ps[m0 + l15][ct * 16 + l4 * 4] = pk;
        }
        // ps rows [m0, m0+16) wave-local -> no barrier

        // ---- PV (64x32, K=64) + coalesced store ----
        const bf16x8 ap0 = *(const bf16x8*)&ps[m0 + l15][l4 * 8];
        const bf16x8 ap1 = *(const bf16x8*)&ps[m0 + l15][32 + l4 * 8];
#pragma unroll
        for (int nt = 0; nt < 2; ++nt) {
            f32x4 oa = {0.f, 0.f, 0.f, 0.f};
            const bf16x8 bv0 = *(const bf16x8*)&vt[nt * 16 + l15][l4 * 8];
            const bf16x8 bv1 = *(const bf16x8*)&vt[nt * 16 + l15][32 + l4 * 8];
            __builtin_amdgcn_s_setprio(1);
            oa = __builtin_amdgcn_mfma_f32_16x16x32_bf16(ap0, bv0, oa, 0, 0, 0);
            oa = __builtin_amdgcn_mfma_f32_16x16x32_bf16(ap1, bv1, oa, 0, 0, 0);
            __builtin_amdgcn_s_setprio(0);
            const int dim = h * HD + nt * 16 + l15;
            const int pxr = m0 + l4 * 4;
            const int py = r0 + (pxr >> 3), pxc = c0 + (pxr & 7);
            float* op = out + (((size_t)(b * CIN + dim)) << 16) + py * IMG + pxc;
            *(f32x4*)op = oa;
        }
        __syncthreads();   // buffers reusable next head
    }
}

__global__ void cvt_w(const float* __restrict__ w, u16* __restrict__ o, int n) {
    const int i = blockIdx.x * 256 + threadIdx.x;
    if (i < n) o[i] = f2bf(w[i]);
}

extern "C" void kernel_launch(void* const* d_in, const int* in_sizes, int n_in,
                              void* d_out, int out_size, void* d_ws, size_t ws_size,
                              hipStream_t stream) {
    const float* x   = (const float*)d_in[0];
    const float* dww = (const float*)d_in[1];
    const float* dwb = (const float*)d_in[2];
    const float* pww = (const float*)d_in[3];
    const float* pwb = (const float*)d_in[4];
    float* out = (float*)d_out;

    const int nw = 3 * CIN * CIN;
    u16* wbf = nullptr;
    if (ws_size >= (size_t)nw * sizeof(u16)) {
        wbf = (u16*)d_ws;
        hipLaunchKernelGGL(cvt_w, dim3(nw / 256), dim3(256), 0, stream, pww, wbf, nw);
    }
    hipLaunchKernelGGL(fused_winattn_mfma, dim3(NWIN), dim3(256), 0, stream,
                       x, dww, dwb, pww, pwb, wbf, out);
}